// Round 5
// baseline (510.810 us; speedup 1.0000x reference)
//
#include <hip/hip_runtime.h>
#include <hip/hip_bf16.h>

#define B_SZ 256
#define S_LEN 512
#define NT 128
#define PAD 127
#define LN2F 0.69314718055994530942f
#define RENORM 0x1p-62f

typedef short bf16x8 __attribute__((ext_vector_type(8)));
typedef float f32x4 __attribute__((ext_vector_type(4)));

union FU { bf16x8 v; unsigned u[4]; };

__device__ __forceinline__ unsigned pkbf(float lo, float hi) {
    __hip_bfloat162 h = __float22bfloat162_rn(make_float2(lo, hi));
    union { __hip_bfloat162 b; unsigned u; } cv; cv.b = h; return cv.u;
}

// ---------------- Pre-pass: P = exp(em) (optional) + numerator ----------------
template<bool PRE>
__global__ __launch_bounds__(256) void crf_pre(
    const float* __restrict__ em, const int* __restrict__ tags,
    const float* __restrict__ startT, const float* __restrict__ endT,
    const float* __restrict__ trans, float* __restrict__ P,
    float* __restrict__ out)
{
    const int b = blockIdx.x, tid = threadIdx.x;
    const float* em_b = em + (size_t)b * S_LEN * NT;

    if (PRE) {
        const float4* s4 = (const float4*)em_b;
        float4* d4 = (float4*)(P + (size_t)b * S_LEN * NT);
        for (int i = tid; i < S_LEN * NT / 4; i += 256) {
            float4 v = s4[i];
            float4 r;
            r.x = __expf(v.x); r.y = __expf(v.y);
            r.z = __expf(v.z); r.w = __expf(v.w);
            d4[i] = r;
        }
    }

    // numerator: gold-path score (round-1-verified logic)
    const int* tg = tags + (size_t)b * S_LEN;
    __shared__ float red[256];
    __shared__ int   redi[256];
    float s = 0.0f; int cnt = 0;
    for (int t = tid; t < S_LEN; t += 256) {
        int tgt = tg[t];
        int m = (tgt != PAD) ? 1 : 0;
        cnt += m;
        if (t > 0) {
            int tgp = tg[t - 1];
            float v = trans[tgp * NT + tgt] + em_b[(size_t)t * NT + tgt];
            s += m ? v : 0.0f;
        } else {
            s += startT[tgt] + em_b[tgt];
        }
    }
    red[tid] = s; redi[tid] = cnt;
    __syncthreads();
    if (tid < 128) { red[tid] += red[tid + 128]; redi[tid] += redi[tid + 128]; }
    __syncthreads();
    if (tid < 64) {
        float v = red[tid] + red[tid + 64];
        int   c = redi[tid] + redi[tid + 64];
        #pragma unroll
        for (int o = 32; o > 0; o >>= 1) {
            v += __shfl_down(v, o, 64);
            c += __shfl_down(c, o, 64);
        }
        if (tid == 0) {
            int last = tg[c - 1];
            atomicAdd(out, (v + endT[last]) * (1.0f / (float)B_SZ));
        }
    }
}

// ---------------- Denominator: barrier-free MFMA forward recursion ----------------
// One wave per 16 batches (grid=16, block=64). Y = X^T (128 states x 16 batches).
// Step: D = E^T(perm-baked, bf16 A-frags) @ Y(bf16 B-frags); X'[j][b] = D*e, masked,
// renormed, kept in C-layout f32; C-layout packets ARE next step's B-frag slots
// (permutation pi(16mt+4q+r)=32(mt&3)+8q+(r+4(mt>>2)) makes the layouts coincide).
template<bool PRE>
__global__ __launch_bounds__(64, 1) void crf_denom_mfma(
    const float* __restrict__ emP,     // P=exp(em) if PRE else raw em
    const int*   __restrict__ tags,
    const float* __restrict__ startT,
    const float* __restrict__ endT,
    const float* __restrict__ trans,
    float* __restrict__ out)
{
    const int g = blockIdx.x;          // batch group: batches g*16 .. g*16+15
    const int l = threadIdx.x;         // lane
    const int p = l & 15;              // batch-within-group / MFMA n,m index
    const int q = l >> 4;              // quad 0..3

    __shared__ unsigned mbits[S_LEN];

    // ---- mask bit-words: bit i of mbits[t] = (tags[g*16+i][t] != PAD) ----
    const int* tgg = tags + (size_t)g * 16 * S_LEN;
    for (int t8 = 0; t8 < 8; ++t8) {
        int t = l * 8 + t8;
        unsigned wbits = 0;
        #pragma unroll
        for (int i = 0; i < 16; ++i)
            wbits |= ((tgg[i * S_LEN + t] != PAD) ? 1u : 0u) << i;
        mbits[t] = wbits;
    }
    __syncthreads();

    // ---- A-fragments: E^T with permutation baked in (bf16, 128 VGPRs) ----
    // A-tile(mt,kt): lane slot j' (k_loc=8q+j'): value = exp(trans[row][col]),
    // row = pi^{-1}(32kt+8q+j') = 16*(kt+4*(j'>>2)) + 4q + (j'&3), col = 16mt+p.
    FU Af[8][4];
    #pragma unroll
    for (int mt = 0; mt < 8; ++mt) {
        #pragma unroll
        for (int kt = 0; kt < 4; ++kt) {
            float v[8];
            #pragma unroll
            for (int jp = 0; jp < 8; ++jp) {
                int row = 16 * (kt + 4 * (jp >> 2)) + 4 * q + (jp & 3);
                int col = 16 * mt + p;
                v[jp] = __expf(trans[row * NT + col]);
            }
            Af[mt][kt].u[0] = pkbf(v[0], v[1]);
            Af[mt][kt].u[1] = pkbf(v[2], v[3]);
            Af[mt][kt].u[2] = pkbf(v[4], v[5]);
            Af[mt][kt].u[3] = pkbf(v[6], v[7]);
        }
    }

    // ---- X_0 (C-layout packets): X[mt].r = X0[j=16mt+4q+r][b=p] ----
    const float* plane = emP + ((size_t)(g * 16 + p)) * (S_LEN * NT) + 4 * q;
    f32x4 X[8];
    #pragma unroll
    for (int mt = 0; mt < 8; ++mt) {
        float4 e0 = *(const float4*)(plane + 16 * mt);   // t = 0
        int jb = 16 * mt + 4 * q;
        float p0 = PRE ? e0.x : __expf(e0.x);
        float p1 = PRE ? e0.y : __expf(e0.y);
        float p2 = PRE ? e0.z : __expf(e0.z);
        float p3 = PRE ? e0.w : __expf(e0.w);
        X[mt].x = __expf(startT[jb + 0]) * p0;
        X[mt].y = __expf(startT[jb + 1]) * p1;
        X[mt].z = __expf(startT[jb + 2]) * p2;
        X[mt].w = __expf(startT[jb + 3]) * p3;
    }

    // ---- B-frags from X packets (zero data movement; see pi above) ----
    FU Bf[4];
    #pragma unroll
    for (int kt = 0; kt < 4; ++kt) {
        Bf[kt].u[0] = pkbf(X[kt].x, X[kt].y);
        Bf[kt].u[1] = pkbf(X[kt].z, X[kt].w);
        Bf[kt].u[2] = pkbf(X[kt + 4].x, X[kt + 4].y);
        Bf[kt].u[3] = pkbf(X[kt + 4].z, X[kt + 4].w);
    }

    // ---- emission prefetch ring: depth 4 (slot = t & 3) ----
    float4 EF[4][8];
    #pragma unroll
    for (int tt = 1; tt <= 4; ++tt)
        #pragma unroll
        for (int mt = 0; mt < 8; ++mt)
            EF[tt & 3][mt] = *(const float4*)(plane + (size_t)tt * NT + 16 * mt);

    const f32x4 zf = {0.f, 0.f, 0.f, 0.f};

#define STEP(T, RN)                                                            \
  {                                                                            \
    const int t_ = (T); const int sl_ = t_ & 3;                                \
    f32x4 acc[8];                                                              \
    _Pragma("unroll")                                                          \
    for (int mt = 0; mt < 8; ++mt) {                                           \
      f32x4 a_ = __builtin_amdgcn_mfma_f32_16x16x32_bf16(Af[mt][0].v, Bf[0].v, zf, 0, 0, 0); \
      a_ = __builtin_amdgcn_mfma_f32_16x16x32_bf16(Af[mt][1].v, Bf[1].v, a_, 0, 0, 0);       \
      a_ = __builtin_amdgcn_mfma_f32_16x16x32_bf16(Af[mt][2].v, Bf[2].v, a_, 0, 0, 0);       \
      a_ = __builtin_amdgcn_mfma_f32_16x16x32_bf16(Af[mt][3].v, Bf[3].v, a_, 0, 0, 0);       \
      acc[mt] = a_;                                                            \
    }                                                                          \
    unsigned mw_ = mbits[t_];                                                  \
    bool m_ = (mw_ >> p) & 1u;                                                 \
    _Pragma("unroll")                                                          \
    for (int mt = 0; mt < 8; ++mt) {                                           \
      float4 e_ = EF[sl_][mt];                                                 \
      float e0 = PRE ? e_.x : __expf(e_.x);                                    \
      float e1 = PRE ? e_.y : __expf(e_.y);                                    \
      float e2 = PRE ? e_.z : __expf(e_.z);                                    \
      float e3 = PRE ? e_.w : __expf(e_.w);                                    \
      float n0 = acc[mt].x * e0, n1 = acc[mt].y * e1;                          \
      float n2 = acc[mt].z * e2, n3 = acc[mt].w * e3;                          \
      X[mt].x = m_ ? n0 : X[mt].x;                                             \
      X[mt].y = m_ ? n1 : X[mt].y;                                             \
      X[mt].z = m_ ? n2 : X[mt].z;                                             \
      X[mt].w = m_ ? n3 : X[mt].w;                                             \
      if (RN) {                                                                \
        X[mt].x *= RENORM; X[mt].y *= RENORM;                                  \
        X[mt].z *= RENORM; X[mt].w *= RENORM;                                  \
      }                                                                        \
    }                                                                          \
    { int tn_ = t_ + 4; if (tn_ > S_LEN - 1) tn_ = S_LEN - 1;                  \
      const float* pt_ = plane + (size_t)tn_ * NT;                             \
      _Pragma("unroll")                                                        \
      for (int mt = 0; mt < 8; ++mt)                                           \
        EF[sl_][mt] = *(const float4*)(pt_ + 16 * mt); }                       \
    _Pragma("unroll")                                                          \
    for (int kt = 0; kt < 4; ++kt) {                                           \
      Bf[kt].u[0] = pkbf(X[kt].x, X[kt].y);                                    \
      Bf[kt].u[1] = pkbf(X[kt].z, X[kt].w);                                    \
      Bf[kt].u[2] = pkbf(X[kt + 4].x, X[kt + 4].y);                            \
      Bf[kt].u[3] = pkbf(X[kt + 4].z, X[kt + 4].w);                            \
    }                                                                          \
  }

    // t = 1..7 (peel), then 63 chunks of 8 with renorm at t = 8c (63 renorms)
    STEP(1, false) STEP(2, false) STEP(3, false) STEP(4, false)
    STEP(5, false) STEP(6, false) STEP(7, false)
    for (int c = 1; c < 64; ++c) {
        const int t0 = c * 8;
        STEP(t0, true)
        STEP(t0 + 1, false) STEP(t0 + 2, false) STEP(t0 + 3, false)
        STEP(t0 + 4, false) STEP(t0 + 5, false) STEP(t0 + 6, false)
        STEP(t0 + 7, false)
    }
#undef STEP

    // ---- denominator: Z_b = sum_j X[j][b] * exp(endT[j]) ----
    float pe = 0.f;
    #pragma unroll
    for (int mt = 0; mt < 8; ++mt) {
        int jb = 16 * mt + 4 * q;
        pe += X[mt].x * __expf(endT[jb + 0]);
        pe += X[mt].y * __expf(endT[jb + 1]);
        pe += X[mt].z * __expf(endT[jb + 2]);
        pe += X[mt].w * __expf(endT[jb + 3]);
    }
    pe += __shfl_xor(pe, 16, 64);
    pe += __shfl_xor(pe, 32, 64);      // lanes 0..15 now hold Z for batch p

    float Zs = (l < 16) ? pe : 1.0f;
    float dv = (l < 16)
             ? (-(63.0f * 62.0f * LN2F + logf(Zs)) * (1.0f / (float)B_SZ))
             : 0.0f;
    #pragma unroll
    for (int off = 32; off > 0; off >>= 1)
        dv += __shfl_down(dv, off, 64);
    if (l == 0) atomicAdd(out, dv);
}

extern "C" void kernel_launch(void* const* d_in, const int* in_sizes, int n_in,
                              void* d_out, int out_size, void* d_ws, size_t ws_size,
                              hipStream_t stream) {
    const float* em     = (const float*)d_in[0];
    const int*   tags   = (const int*)d_in[1];
    const float* startT = (const float*)d_in[2];
    const float* endT   = (const float*)d_in[3];
    const float* trans  = (const float*)d_in[4];
    float* out = (float*)d_out;

    const size_t needP = (size_t)B_SZ * S_LEN * NT * sizeof(float);
    const bool pre = (ws_size >= needP);

    hipMemsetAsync(out, 0, sizeof(float), stream);
    if (pre) {
        float* P = (float*)d_ws;
        crf_pre<true><<<B_SZ, 256, 0, stream>>>(em, tags, startT, endT, trans, P, out);
        crf_denom_mfma<true><<<B_SZ / 16, 64, 0, stream>>>(P, tags, startT, endT, trans, out);
    } else {
        crf_pre<false><<<B_SZ, 256, 0, stream>>>(em, tags, startT, endT, trans, nullptr, out);
        crf_denom_mfma<false><<<B_SZ / 16, 64, 0, stream>>>(em, tags, startT, endT, trans, out);
    }
}